// Round 2
// baseline (1994.911 us; speedup 1.0000x reference)
//
#include <hip/hip_runtime.h>

#define BROWS 131072
#define MDIM 64
#define NDIM 121
#define STAGES 9

// ws layout (floats):
//   [0,     4096)  R    (64x64)
//   [4096, 11840)  PhiT (121x64)
//   [12288, 20032) GT   (121x64)   GT[n][k] = (F_9 * Phi)[k][n]

// ---------------------------------------------------------------- kernel A
__global__ void prep_kernel(const float* __restrict__ Phi,
                            float* __restrict__ R,
                            float* __restrict__ PhiT) {
    int id = blockIdx.x * blockDim.x + threadIdx.x;
    if (id < MDIM * MDIM) {
        int i = id >> 6, j = id & 63;
        const float* a = Phi + i * NDIM;
        const float* b = Phi + j * NDIM;
        float s0 = 0.f, s1 = 0.f, s2 = 0.f, s3 = 0.f;
        for (int n = 0; n < 120; n += 4) {
            s0 += a[n + 0] * b[n + 0];
            s1 += a[n + 1] * b[n + 1];
            s2 += a[n + 2] * b[n + 2];
            s3 += a[n + 3] * b[n + 3];
        }
        R[id] = (s0 + s1) + (s2 + s3) + a[120] * b[120];
    }
    int id2 = id - MDIM * MDIM;
    if (id2 >= 0 && id2 < NDIM * MDIM) {
        int n = id2 >> 6, k = id2 & 63;
        PhiT[id2] = Phi[k * NDIM + n];
    }
}

// ---------------------------------------------------------------- kernel B
// F-recurrence: 1 block, 4 waves, lane = row i. F row in VGPRs (static idx
// only). R resident in LDS, read as same-address broadcast ds_read_b128.
// Updated columns exchanged via transposed padded sFT[j*65+i] (bank (j+i)%32
// -> 2-way, free). Jacobi order: writes go to sFT only; f[] refilled after
// the barrier.
__global__ __launch_bounds__(256) void fmat_kernel(const float* __restrict__ R,
                                                   const float* __restrict__ PhiT,
                                                   const float* __restrict__ gammas,
                                                   float* __restrict__ GT) {
    __shared__ float smem[8272];
    float* sR  = smem;          // [64][64]
    float* sFT = smem + 4096;   // [64][65]  sFT[j*65+i] = F[i][j]
    float* sG  = smem + 8256;   // [9]
    const int tid = threadIdx.x;
    const int lane = tid & 63;
    const int wave = tid >> 6;

    for (int q = tid; q < 1024; q += 256)
        ((float4*)sR)[q] = ((const float4*)R)[q];
    if (tid < STAGES) sG[tid] = gammas[tid];
    for (int q = tid; q < 4096; q += 256) {
        int j = q >> 6, i = q & 63;
        sFT[j * 65 + i] = (i == j) ? 1.f : 0.f;
    }
    float f[64];
#pragma unroll
    for (int m = 0; m < 64; ++m) f[m] = (lane == m) ? 1.f : 0.f;
    __syncthreads();

    for (int s = 0; s < STAGES; ++s) {
        float gam = sG[s];
        for (int u = 0; u < 16; ++u) {
            int j = (wave << 4) + u;                       // this wave's column
            const float4* Rr = (const float4*)(sR + j * 64);
            float a0 = 0.f, a1 = 0.f, a2 = 0.f, a3 = 0.f;
#pragma unroll
            for (int q = 0; q < 16; ++q) {
                float4 rv = Rr[q];                          // broadcast read
                a0 += f[4 * q + 0] * rv.x;
                a1 += f[4 * q + 1] * rv.y;
                a2 += f[4 * q + 2] * rv.z;
                a3 += f[4 * q + 3] * rv.w;
            }
            float mij = (a0 + a1) + (a2 + a3);              // (F R)[i][j]
            float d = 1.f / (sR[j * 64 + j] + gam);
            float del = (lane == j) ? 1.f : 0.f;
            sFT[j * 65 + lane] += d * (del - mij);          // F_{s+1}[i][j]
        }
        __syncthreads();
#pragma unroll
        for (int m = 0; m < 64; ++m) f[m] = sFT[m * 65 + lane];
        __syncthreads();
    }

    // reuse smem[0..7744) to stage PhiT, then G^T = (F * Phi)^T
    for (int q = tid; q < 1936; q += 256)
        ((float4*)smem)[q] = ((const float4*)PhiT)[q];
    __syncthreads();
    for (int n = wave; n < NDIM; n += 4) {
        const float4* pr = (const float4*)(smem + n * 64);
        float a0 = 0.f, a1 = 0.f, a2 = 0.f, a3 = 0.f;
#pragma unroll
        for (int q = 0; q < 16; ++q) {
            float4 pv = pr[q];                              // broadcast read
            a0 += f[4 * q + 0] * pv.x;
            a1 += f[4 * q + 1] * pv.y;
            a2 += f[4 * q + 2] * pv.z;
            a3 += f[4 * q + 3] * pv.w;
        }
        GT[n * 64 + lane] = (a0 + a1) + (a2 + a3);
    }
}

// ---------------------------------------------------------------- kernel C
// theta[r][n] = sum_k y[r][k] * GT[n][k]. 2 rows/thread (halves GT
// broadcast traffic). GT in LDS, padded to 128 rows (zero-filled) so the
// column loop is always 16 and fully unrolled (accB stays in registers).
// Stores staged through LDS (row stride 484B can't coalesce directly).
__global__ __launch_bounds__(256, 2) void gemm_kernel(const float* __restrict__ y,
                                                      const float* __restrict__ GT,
                                                      float* __restrict__ out) {
    __shared__ float sGT[128 * 64];   // 32 KB
    __shared__ float so[256 * 17];    // 17 KB
    const int tid = threadIdx.x;
    const int row0 = blockIdx.x * 512;

    for (int q = tid; q < 1936; q += 256)
        ((float4*)sGT)[q] = ((const float4*)GT)[q];
    for (int q = tid; q < 448; q += 256)
        sGT[7744 + q] = 0.f;                      // rows 121..127 zero

    float yA[64], yB[64];
    {
        const float4* ya = (const float4*)(y + (row0 + tid) * 64);
        const float4* yb = (const float4*)(y + (row0 + 256 + tid) * 64);
#pragma unroll
        for (int q = 0; q < 16; ++q) {
            float4 t = ya[q];
            yA[4 * q + 0] = t.x; yA[4 * q + 1] = t.y;
            yA[4 * q + 2] = t.z; yA[4 * q + 3] = t.w;
            float4 v = yb[q];
            yB[4 * q + 0] = v.x; yB[4 * q + 1] = v.y;
            yB[4 * q + 2] = v.z; yB[4 * q + 3] = v.w;
        }
    }
    __syncthreads();

    const int col = tid & 15, rb = tid >> 4;
    for (int nc = 0; nc < 8; ++nc) {
        const int n0 = nc << 4;
        const int cc = (nc == 7) ? 9 : 16;
        float accB[16];
#pragma unroll
        for (int u = 0; u < 16; ++u) {
            const float4* gr = (const float4*)(sGT + (n0 + u) * 64);
            float a0 = 0.f, a1 = 0.f, a2 = 0.f, a3 = 0.f;
            float b0 = 0.f, b1 = 0.f, b2 = 0.f, b3 = 0.f;
#pragma unroll
            for (int q = 0; q < 16; ++q) {
                float4 g = gr[q];                           // broadcast read
                a0 += yA[4 * q + 0] * g.x; a1 += yA[4 * q + 1] * g.y;
                a2 += yA[4 * q + 2] * g.z; a3 += yA[4 * q + 3] * g.w;
                b0 += yB[4 * q + 0] * g.x; b1 += yB[4 * q + 1] * g.y;
                b2 += yB[4 * q + 2] * g.z; b3 += yB[4 * q + 3] * g.w;
            }
            so[tid * 17 + u] = (a0 + a1) + (a2 + a3);
            accB[u] = (b0 + b1) + (b2 + b3);
        }
        __syncthreads();
        if (col < cc) {
#pragma unroll
            for (int rep = 0; rep < 16; ++rep) {
                int rl = (rep << 4) + rb;
                out[(row0 + rl) * NDIM + n0 + col] = so[rl * 17 + col];
            }
        }
        __syncthreads();
#pragma unroll
        for (int u = 0; u < 16; ++u) so[tid * 17 + u] = accB[u];
        __syncthreads();
        if (col < cc) {
#pragma unroll
            for (int rep = 0; rep < 16; ++rep) {
                int rl = (rep << 4) + rb;
                out[(row0 + 256 + rl) * NDIM + n0 + col] = so[rl * 17 + col];
            }
        }
        __syncthreads();
    }
}

extern "C" void kernel_launch(void* const* d_in, const int* in_sizes, int n_in,
                              void* d_out, int out_size, void* d_ws, size_t ws_size,
                              hipStream_t stream) {
    const float* y      = (const float*)d_in[0];
    const float* Phi    = (const float*)d_in[1];
    const float* gammas = (const float*)d_in[2];
    float* out = (float*)d_out;

    float* R    = (float*)d_ws;
    float* PhiT = R + 4096;
    float* GT   = R + 12288;

    prep_kernel<<<(MDIM * MDIM + NDIM * MDIM + 255) / 256, 256, 0, stream>>>(Phi, R, PhiT);
    fmat_kernel<<<1, 256, 0, stream>>>(R, PhiT, gammas, GT);
    gemm_kernel<<<BROWS / 512, 256, 0, stream>>>(y, GT, out);
}

// Round 5
// 255.683 us; speedup vs baseline: 7.8023x; 7.8023x over previous
//
#include <hip/hip_runtime.h>

#define BROWS 131072
#define MDIM 64
#define NDIM 121
#define STAGES 9
#define RPB 32   // rows per block in gemm

// ws layout (floats):
//   [0,     4096)  R    (64x64)
//   [4096, 11840)  PhiT (121x64)
//   [12288, 20032) GT   (121x64)   GT[n][k] = (F_9 * Phi)[k][n]

// ---------------------------------------------------------------- kernel A
__global__ void prep_kernel(const float* __restrict__ Phi,
                            float* __restrict__ R,
                            float* __restrict__ PhiT) {
    int id = blockIdx.x * blockDim.x + threadIdx.x;
    if (id < MDIM * MDIM) {
        int i = id >> 6, j = id & 63;
        const float* a = Phi + i * NDIM;
        const float* b = Phi + j * NDIM;
        float s0 = 0.f, s1 = 0.f, s2 = 0.f, s3 = 0.f;
        for (int n = 0; n < 120; n += 4) {
            s0 += a[n + 0] * b[n + 0];
            s1 += a[n + 1] * b[n + 1];
            s2 += a[n + 2] * b[n + 2];
            s3 += a[n + 3] * b[n + 3];
        }
        R[id] = (s0 + s1) + (s2 + s3) + a[120] * b[120];
    }
    int id2 = id - MDIM * MDIM;
    if (id2 >= 0 && id2 < NDIM * MDIM) {
        int n = id2 >> 6, k = id2 & 63;
        PhiT[id2] = Phi[k * NDIM + n];
    }
}

// ---------------------------------------------------------------- kernel B
// F-recurrence: 1 block, 4 waves, lane = row i. F row in VGPRs (static idx
// only). R resident in LDS (broadcast ds_read_b128). Updated columns
// exchanged via transposed padded sFT[j*65+i].
__global__ __launch_bounds__(256) void fmat_kernel(const float* __restrict__ R,
                                                   const float* __restrict__ PhiT,
                                                   const float* __restrict__ gammas,
                                                   float* __restrict__ GT) {
    __shared__ float smem[8272];
    float* sR  = smem;          // [64][64]
    float* sFT = smem + 4096;   // [64][65]  sFT[j*65+i] = F[i][j]
    float* sG  = smem + 8256;   // [9]
    const int tid = threadIdx.x;
    const int lane = tid & 63;
    const int wave = tid >> 6;

    for (int q = tid; q < 1024; q += 256)
        ((float4*)sR)[q] = ((const float4*)R)[q];
    if (tid < STAGES) sG[tid] = gammas[tid];
    for (int q = tid; q < 4096; q += 256) {
        int j = q >> 6, i = q & 63;
        sFT[j * 65 + i] = (i == j) ? 1.f : 0.f;
    }
    float f[64];
#pragma unroll
    for (int m = 0; m < 64; ++m) f[m] = (lane == m) ? 1.f : 0.f;
    __syncthreads();

    for (int s = 0; s < STAGES; ++s) {
        float gam = sG[s];
        for (int u = 0; u < 16; ++u) {
            int j = (wave << 4) + u;
            const float4* Rr = (const float4*)(sR + j * 64);
            float a0 = 0.f, a1 = 0.f, a2 = 0.f, a3 = 0.f;
#pragma unroll
            for (int q = 0; q < 16; ++q) {
                float4 rv = Rr[q];                          // broadcast read
                a0 += f[4 * q + 0] * rv.x;
                a1 += f[4 * q + 1] * rv.y;
                a2 += f[4 * q + 2] * rv.z;
                a3 += f[4 * q + 3] * rv.w;
            }
            float mij = (a0 + a1) + (a2 + a3);              // (F R)[i][j]
            float d = 1.f / (sR[j * 64 + j] + gam);
            float del = (lane == j) ? 1.f : 0.f;
            sFT[j * 65 + lane] += d * (del - mij);          // F_{s+1}[i][j]
        }
        __syncthreads();
#pragma unroll
        for (int m = 0; m < 64; ++m) f[m] = sFT[m * 65 + lane];
        __syncthreads();
    }

    // reuse smem[0..7744) to stage PhiT, then G^T = (F * Phi)^T
    for (int q = tid; q < 1936; q += 256)
        ((float4*)smem)[q] = ((const float4*)PhiT)[q];
    __syncthreads();
    for (int n = wave; n < NDIM; n += 4) {
        const float4* pr = (const float4*)(smem + n * 64);
        float a0 = 0.f, a1 = 0.f, a2 = 0.f, a3 = 0.f;
#pragma unroll
        for (int q = 0; q < 16; ++q) {
            float4 pv = pr[q];                              // broadcast read
            a0 += f[4 * q + 0] * pv.x;
            a1 += f[4 * q + 1] * pv.y;
            a2 += f[4 * q + 2] * pv.z;
            a3 += f[4 * q + 3] * pv.w;
        }
        GT[n * 64 + lane] = (a0 + a1) + (a2 + a3);
    }
}

// ---------------------------------------------------------------- kernel C
// Column-owner GEMM: block = 128 threads, thread owns output column `col`
// and keeps G[:,col] (= GT[col][0..64)) in 64 VGPRs. The y row address
// depends only on blockIdx + loop counter -> wave-uniform -> s_load
// (SGPR-broadcast operand into v_fmac). Stores are contiguous 484B per
// row, no LDS.
__global__ __launch_bounds__(128) void gemm_kernel(const float* __restrict__ y,
                                                   const float* __restrict__ GT,
                                                   float* __restrict__ out) {
    const int tid = threadIdx.x;                 // 0..127
    const int col = (tid < NDIM) ? tid : (NDIM - 1);

    float g[64];
    {
        const float4* gp = (const float4*)(GT + col * 64);
#pragma unroll
        for (int q = 0; q < 16; ++q) {
            float4 t = gp[q];
            g[4 * q + 0] = t.x; g[4 * q + 1] = t.y;
            g[4 * q + 2] = t.z; g[4 * q + 3] = t.w;
        }
    }

    const long long r0 = (long long)blockIdx.x * RPB;
#pragma unroll 4
    for (int i = 0; i < RPB; ++i) {
        const long long r = r0 + i;
        const float4* yr = (const float4*)(y + r * 64);   // wave-uniform
        float a0 = 0.f, a1 = 0.f, a2 = 0.f, a3 = 0.f;
#pragma unroll
        for (int q = 0; q < 16; ++q) {
            float4 t = yr[q];                             // -> s_load_dwordx4
            a0 += g[4 * q + 0] * t.x;
            a1 += g[4 * q + 1] * t.y;
            a2 += g[4 * q + 2] * t.z;
            a3 += g[4 * q + 3] * t.w;
        }
        if (tid < NDIM)
            out[r * NDIM + tid] = (a0 + a1) + (a2 + a3);
    }
}

extern "C" void kernel_launch(void* const* d_in, const int* in_sizes, int n_in,
                              void* d_out, int out_size, void* d_ws, size_t ws_size,
                              hipStream_t stream) {
    const float* y      = (const float*)d_in[0];
    const float* Phi    = (const float*)d_in[1];
    const float* gammas = (const float*)d_in[2];
    float* out = (float*)d_out;

    float* R    = (float*)d_ws;
    float* PhiT = R + 4096;
    float* GT   = R + 12288;

    prep_kernel<<<(MDIM * MDIM + NDIM * MDIM + 255) / 256, 256, 0, stream>>>(Phi, R, PhiT);
    fmat_kernel<<<1, 256, 0, stream>>>(R, PhiT, gammas, GT);
    gemm_kernel<<<BROWS / RPB, 128, 0, stream>>>(y, GT, out);
}